// Round 12
// baseline (346.103 us; speedup 1.0000x reference)
//
#include <hip/hip_runtime.h>
#include <hip/hip_bf16.h>
#include <stdint.h>

// ---------------------------------------------------------------------------
// TensorizedGRU: m[b,l] = sum_{j,k} s[b,j] x[b,k] W[l,j,k]  (l in [0,256): W1||W2)
// R12: LDS-free gemm + TLP + L1 B-sharing.
//  - wave = 64m x 16n (one n16 frag): racc 16 + a 32 + B ping-pong 16 +
//    sv ping-pong 32 VGPR -> ~110, fits 4 waves/SIMD.
//  - grid 2048 = 8ks x 4ntq x 64mt, mt FASTEST within (ks,ntq): co-resident
//    blocks on a CU share the same B-stream -> L1 hits, per-CU L2 traffic flat.
//  - s values from s_perm[j][b] f32 in global (prep transposes): broadcast
//    VMEM loads, prefetched; gemm has NO LDS, NO barrier.
//  - Fragment-ordered Wt (n16 x k64 x kst 1KB frags) as R9; XCD-pinned ks;
//    regular stores.
// ws layout:
//   Wt    bf16 [256][65536]   @ 0            (33,554,432 B) frag-ordered
//   x_bf  bf16 [4096][256]    @ 32MiB+2MiB   ( 2,097,152 B)
//   Mpart f32 [8][4096][256]  @ +2MiB        (33,554,432 B)
//   s_perm f32 [256][4096]    @ +33.5MiB     ( 4,194,304 B) transposed s
// ---------------------------------------------------------------------------

typedef short bf8 __attribute__((ext_vector_type(8)));   // 8 bf16 = 4 VGPRs
typedef float f32x4 __attribute__((ext_vector_type(4)));

static constexpr size_t WT_OFF  = 0;
static constexpr size_t XBF_OFF = 33554432 + 2097152;
static constexpr size_t MP_OFF  = XBF_OFF + 2097152;
static constexpr size_t SP_OFF  = MP_OFF + 33554432;

// round-to-nearest-even f32 -> bf16 (finite inputs only)
__device__ __forceinline__ unsigned f2bf(float f) {
    unsigned u = __builtin_bit_cast(unsigned, f);
    return (u + 0x7fffu + ((u >> 16) & 1u)) >> 16;
}
__device__ __forceinline__ unsigned pack2bf(float a, float b) {
    return f2bf(a) | (f2bf(b) << 16);
}

// ---------------- prep: frag-ordered Wt + x cast + s transpose --------------
// bx <  8192 : Wt fragment f = bx*4+wave (n16 x k64 x kst cut, R9 layout)
// bx in [8192,9216): x = in0||in1 -> bf16
// bx in [9216,9472): s_perm 64b x 64j transpose tiles
__global__ void prep_wx(const float* __restrict__ W1, const float* __restrict__ W2,
                        const float* __restrict__ in0, const float* __restrict__ in1,
                        const float* __restrict__ st0, const float* __restrict__ st1,
                        uint4* __restrict__ Wt, unsigned* __restrict__ x_bf,
                        float* __restrict__ Sperm) {
    int bx = blockIdx.x;
    if (bx < 8192) {
        const int tid  = threadIdx.x;
        const int lane = tid & 63, wave = tid >> 6;
        const unsigned f = bx * 4 + wave;
        const unsigned n16 = f >> 11;
        const unsigned kchunk = (f >> 1) & 1023u;
        const unsigned kst = f & 1u;
        const unsigned n = n16 * 16 + (lane & 15);
        const unsigned K = kchunk * 64 + kst * 32 + (lane >> 4) * 8;
        const float* src = (n < 128 ? W1 + ((size_t)n << 16)
                                    : W2 + ((size_t)(n - 128) << 16)) + K;
        float4 a = ((const float4*)src)[0];
        float4 b = ((const float4*)src)[1];
        uint4 o;
        o.x = pack2bf(a.x, a.y); o.y = pack2bf(a.z, a.w);
        o.z = pack2bf(b.x, b.y); o.w = pack2bf(b.z, b.w);
        Wt[(size_t)f * 64 + lane] = o;        // contiguous 1KB per wave
    } else if (bx < 9216) {
        unsigned v = (bx - 8192) * 256 + threadIdx.x; // 262,144 units of 4 elems
        unsigned b = v >> 6;
        unsigned j4 = (v & 63u) * 4u;
        const float* src = (j4 < 128) ? (in0 + (size_t)b * 128 + j4)
                                      : (in1 + (size_t)b * 128 + (j4 - 128));
        float4 a = *(const float4*)src;
        uint2 o;
        o.x = pack2bf(a.x, a.y);
        o.y = pack2bf(a.z, a.w);
        ((uint2*)x_bf)[v] = o;
    } else {
        // s transpose: tile (b0t..+64) x (j0..+64)
        const int blk = bx - 9216;            // 0..255
        const int b0t = (blk >> 2) * 64;
        const int j0 = (blk & 3) * 64;
        const int t = threadIdx.x;
        __shared__ float Lt[64][65];
        {
            int r = t >> 2, c4 = (t & 3) * 16;
            const float* srow = (j0 < 128) ? st0 + (size_t)(b0t + r) * 128 + j0
                                           : st1 + (size_t)(b0t + r) * 128 + (j0 - 128);
            #pragma unroll
            for (int i = 0; i < 4; ++i) {
                float4 v = *(const float4*)(srow + c4 + i * 4);
                Lt[r][c4 + i * 4 + 0] = v.x;
                Lt[r][c4 + i * 4 + 1] = v.y;
                Lt[r][c4 + i * 4 + 2] = v.z;
                Lt[r][c4 + i * 4 + 3] = v.w;
            }
        }
        __syncthreads();
        {
            int bq = t & 15;                  // b-quad within tile
            #pragma unroll
            for (int jj = 0; jj < 4; ++jj) {
                int j = (t >> 4) + jj * 16;
                float4 o;
                o.x = Lt[bq * 4 + 0][j];
                o.y = Lt[bq * 4 + 1][j];
                o.z = Lt[bq * 4 + 2][j];
                o.w = Lt[bq * 4 + 3][j];
                *(float4*)(Sperm + (size_t)(j0 + j) * 4096 + b0t + bq * 4) = o;
            }
        }
    }
}

// ---------------- main GEMM: 64m x 64n block, grid 2048, LDS-free -----------
// bx = ks + 8*(mt + 64*ntq): ks = bx&7 (XCD-pinned); mt fastest -> co-resident
// blocks share B-stream via L1. Wave w owns n16 = ntq*4 + w.
__launch_bounds__(256, 2)
__global__ void gemm_p(const unsigned char* __restrict__ Wt,
                       const float* __restrict__ Sperm,
                       const __hip_bfloat16* __restrict__ x_bf,
                       float* __restrict__ Mpart) {
    const int bx = blockIdx.x;
    const int ks = bx & 7;                  // split-K slice, pinned per XCD
    const int rem = bx >> 3;
    const int mt = rem & 63;
    const int ntq = rem >> 6;               // 0..3
    const int b0 = mt << 6;
    const int tid  = threadIdx.x;
    const int lane = tid & 63, wave = tid >> 6;
    const int l15 = lane & 15, l4 = lane >> 4;

    // B-frag base: n16 = ntq*4 + wave; frag addr = ((n16*1024+kchunk)*2+kst)*1024 + lane*16
    const int n16 = ntq * 4 + wave;
    const unsigned char* rb = Wt + ((size_t)n16 << 21) + lane * 16;
    // s broadcast base: Sperm[jg][b0 + mf*16 + l4*4 ..+4), jg = ks*32 + j
    const float* sp = Sperm + ((size_t)(ks * 32) << 12) + b0 + l4 * 4;

    f32x4 racc[4];
    #pragma unroll
    for (int mf = 0; mf < 4; ++mf)
        racc[mf] = (f32x4){0.f, 0.f, 0.f, 0.f};
    const f32x4 zacc = (f32x4){0.f, 0.f, 0.f, 0.f};

    // chunk c in [0,128): q = c>>5 (x-quadrant), j = c&31 (local j)
    auto kof = [&](int c) { return (size_t)(((ks * 32 + (c & 31)) * 4 + (c >> 5)) * 2048); };

    bf8 buf[2][2];                          // [ping][kst]
    f32x4 svb[2][4];                        // [ping][mf]
    #pragma unroll
    for (int kst = 0; kst < 2; ++kst)
        buf[0][kst] = *(const bf8*)(rb + kof(0) + kst * 1024);
    #pragma unroll
    for (int mf = 0; mf < 4; ++mf)
        svb[0][mf] = *(const f32x4*)(sp + mf * 16);   // j=0

    bf8 a[4][2];                            // x A-frags, reloaded at q boundary

    #pragma unroll 2
    for (int c = 0; c < 128; ++c) {
        const int pp = c & 1;
        const int q = c >> 5, j = c & 31;
        if (j == 0) {                       // new x-quadrant: reload A-frags
            const __hip_bfloat16* xb = x_bf + q * 64 + l4 * 8;
            #pragma unroll
            for (int mf = 0; mf < 4; ++mf)
                #pragma unroll
                for (int kst = 0; kst < 2; ++kst)
                    a[mf][kst] = *(const bf8*)(xb + (size_t)(b0 + mf * 16 + l15) * 256 + kst * 32);
        }
        // prefetch next chunk's B-frags + s values (wrap harmless)
        {
            const int c1 = (c + 1) & 127;
            const size_t k1 = kof(c1);
            #pragma unroll
            for (int kst = 0; kst < 2; ++kst)
                buf[pp ^ 1][kst] = *(const bf8*)(rb + k1 + kst * 1024);
            const int j1 = c1 & 31;
            #pragma unroll
            for (int mf = 0; mf < 4; ++mf)
                svb[pp ^ 1][mf] = *(const f32x4*)(sp + ((size_t)j1 << 12) + mf * 16);
        }
        // 8 MFMA + f32 scale-accumulate
        bf8 bf0 = buf[pp][0];
        bf8 bf1 = buf[pp][1];
        #pragma unroll
        for (int mf = 0; mf < 4; ++mf) {
            f32x4 m0 = __builtin_amdgcn_mfma_f32_16x16x32_bf16(a[mf][0], bf0, zacc, 0, 0, 0);
            m0 = __builtin_amdgcn_mfma_f32_16x16x32_bf16(a[mf][1], bf1, m0, 0, 0, 0);
            racc[mf] += svb[pp][mf] * m0;
        }
    }

    // split-K partial stores (regular stores: producer->consumer coherence)
    float* mp = Mpart + ((size_t)ks << 20);
    const int nn = n16 * 16 + l15;
    #pragma unroll
    for (int mf = 0; mf < 4; ++mf) {
        int b = b0 + mf * 16 + l4 * 4;
        #pragma unroll
        for (int r = 0; r < 4; ++r)
            mp[(size_t)(b + r) * 256 + nn] = racc[mf][r];
    }
}

// ---------------- epilogue: reduce split-K, s@W3, activations, blend --------
__global__ void epilogue(const float* __restrict__ st0, const float* __restrict__ st1,
                         const float* __restrict__ b1, const float* __restrict__ b2,
                         const float* __restrict__ W3, const float* __restrict__ Mpart,
                         float* __restrict__ out) {
    const int tid = threadIdx.x;
    const int h = tid & 127, rg = tid >> 7;          // rg in {0,1}
    const int bbase = blockIdx.x * 8;                // 8 rows per block
    __shared__ float srow[8][256];
    #pragma unroll
    for (int i = 0; i < 8; ++i) {
        int idx = i * 256 + tid;
        int r = idx >> 8, j = idx & 255;
        float v = (j < 128) ? st0[(size_t)(bbase + r) * 128 + j]
                            : st1[(size_t)(bbase + r) * 128 + (j - 128)];
        srow[r][j] = v;
    }
    __syncthreads();
    float acc0 = 0.f, acc1 = 0.f, acc2 = 0.f, acc3 = 0.f;
    for (int j = 0; j < 256; ++j) {
        float w = W3[j * 128 + h];
        acc0 += srow[rg][j] * w;
        acc1 += srow[rg + 2][j] * w;
        acc2 += srow[rg + 4][j] * w;
        acc3 += srow[rg + 6][j] * w;
    }
    float accs[4] = {acc0, acc1, acc2, acc3};
    float bb1 = b1[h], bb2 = b2[h];
    #pragma unroll
    for (int i = 0; i < 4; ++i) {
        int b = bbase + rg + i * 2;
        float m1 = 0.f, m2 = 0.f;
        #pragma unroll
        for (int k = 0; k < 8; ++k) {
            m1 += Mpart[((size_t)k << 20) + (size_t)b * 256 + h];
            m2 += Mpart[((size_t)k << 20) + (size_t)b * 256 + 128 + h];
        }
        float u = 1.0f / (1.0f + expf(-(m2 + bb2)));
        float t = tanhf(m1 + bb1);
        out[(size_t)b * 128 + h] = u * t + (1.0f - u) * accs[i];
    }
}

extern "C" void kernel_launch(void* const* d_in, const int* in_sizes, int n_in,
                              void* d_out, int out_size, void* d_ws, size_t ws_size,
                              hipStream_t stream) {
    const float* in0 = (const float*)d_in[0];
    const float* in1 = (const float*)d_in[1];
    const float* st0 = (const float*)d_in[2];
    const float* st1 = (const float*)d_in[3];
    const float* W1  = (const float*)d_in[4];
    const float* b1  = (const float*)d_in[5];
    const float* W2  = (const float*)d_in[6];
    const float* b2  = (const float*)d_in[7];
    const float* W3  = (const float*)d_in[8];
    float* out = (float*)d_out;
    char* ws = (char*)d_ws;

    unsigned char* Wt   = (unsigned char*)(ws + WT_OFF);
    unsigned*      x_bf = (unsigned*)(ws + XBF_OFF);
    float*         Mp   = (float*)(ws + MP_OFF);
    float*         Sp   = (float*)(ws + SP_OFF);

    prep_wx<<<9472, 256, 0, stream>>>(W1, W2, in0, in1, st0, st1,
                                      (uint4*)Wt, x_bf, Sp);
    gemm_p<<<2048, 256, 0, stream>>>(Wt, Sp, (const __hip_bfloat16*)x_bf, Mp);
    epilogue<<<512, 256, 0, stream>>>(st0, st1, b1, b2, W3, Mp, out);
}

// Round 13
// 261.909 us; speedup vs baseline: 1.3215x; 1.3215x over previous
//
#include <hip/hip_runtime.h>
#include <hip/hip_bf16.h>
#include <stdint.h>

// ---------------------------------------------------------------------------
// TensorizedGRU: m[b,l] = sum_{j,k} s[b,j] x[b,k] W[l,j,k]  (l in [0,256): W1||W2)
// R13 = R9 (best: 139us) + DEPTH-4 circular B prefetch.
// R12 lesson: TLP scaling is neutral (wave tile shrinks with wave count);
// the limiter is prefetch depth vs ~1500-2000cyc loaded-L2 latency. Depth-4
// puts ~3 chunks (~1860cyc) of B-loads in flight per wave (vmcnt never
// drains - AITER pattern), at 2 blocks/CU as R9.
//  - wave = 128m x 32n, block 128x128, grid 512, 16x16x32 MFMA.
//  - Fragment-ordered Wt (n16 x k64 x kst 1KB frags), coalesced wave-per-frag
//    producer; XCD-pinned split-K (ks = bx&7); barrier-free K-loop (one
//    initial __syncthreads for s-tile); regular stores.
// ws layout:
//   Wt   bf16 [256][65536]  @ 0          (33,554,432 B)  frag-ordered
//   x_bf bf16 [4096][256]   @ 32MiB+2MiB ( 2,097,152 B)
//   Mpart f32 [8][4096][256]@ +2MiB      (33,554,432 B)
// ---------------------------------------------------------------------------

typedef short bf8 __attribute__((ext_vector_type(8)));   // 8 bf16 = 4 VGPRs
typedef float f32x4 __attribute__((ext_vector_type(4)));

static constexpr size_t WT_OFF  = 0;
static constexpr size_t XBF_OFF = 33554432 + 2097152;
static constexpr size_t MP_OFF  = XBF_OFF + 2097152;

// round-to-nearest-even f32 -> bf16 (finite inputs only)
__device__ __forceinline__ unsigned f2bf(float f) {
    unsigned u = __builtin_bit_cast(unsigned, f);
    return (u + 0x7fffu + ((u >> 16) & 1u)) >> 16;
}
__device__ __forceinline__ unsigned pack2bf(float a, float b) {
    return f2bf(a) | (f2bf(b) << 16);
}

// ---------------- prep: fragment-ordered Wt (wave-per-frag) + x cast --------
// Fragment f = ((n16*1024 + kchunk)*2 + kst), f in [0, 32768).
// Lane l supplies B[n = n16*16 + (l&15)][k = kchunk*64 + kst*32 + (l>>4)*8 ..+8).
__global__ void prep_wx(const float* __restrict__ W1, const float* __restrict__ W2,
                        const float* __restrict__ in0, const float* __restrict__ in1,
                        uint4* __restrict__ Wt, unsigned* __restrict__ x_bf) {
    int bx = blockIdx.x;
    if (bx < 8192) {
        const int tid  = threadIdx.x;
        const int lane = tid & 63, wave = tid >> 6;
        const unsigned f = bx * 4 + wave;
        const unsigned n16 = f >> 11;
        const unsigned kchunk = (f >> 1) & 1023u;
        const unsigned kst = f & 1u;
        const unsigned n = n16 * 16 + (lane & 15);
        const unsigned K = kchunk * 64 + kst * 32 + (lane >> 4) * 8;
        const float* src = (n < 128 ? W1 + ((size_t)n << 16)
                                    : W2 + ((size_t)(n - 128) << 16)) + K;
        float4 a = ((const float4*)src)[0];
        float4 b = ((const float4*)src)[1];
        uint4 o;
        o.x = pack2bf(a.x, a.y); o.y = pack2bf(a.z, a.w);
        o.z = pack2bf(b.x, b.y); o.w = pack2bf(b.z, b.w);
        Wt[(size_t)f * 64 + lane] = o;        // contiguous 1KB per wave
    } else {
        unsigned v = (bx - 8192) * 256 + threadIdx.x; // 262,144 units of 4 elems
        unsigned b = v >> 6;
        unsigned j4 = (v & 63u) * 4u;
        const float* src = (j4 < 128) ? (in0 + (size_t)b * 128 + j4)
                                      : (in1 + (size_t)b * 128 + (j4 - 128));
        float4 a = *(const float4*)src;
        uint2 o;
        o.x = pack2bf(a.x, a.y);
        o.y = pack2bf(a.z, a.w);
        ((uint2*)x_bf)[v] = o;
    }
}

// ---------------- main GEMM: 128x128 tile, split-K=8, depth-4 prefetch ------
// grid 512: ks = bx&7 (XCD-pinned), nt = (bx>>3)&1, mt = bx>>4 (0..31).
// block 256 = 4 waves; wave w owns n-cols [w*32, w*32+32), all 128 m-rows.
__launch_bounds__(256, 2)
__global__ void gemm_p(const unsigned char* __restrict__ Wt,
                       const float* __restrict__ st0, const float* __restrict__ st1,
                       const __hip_bfloat16* __restrict__ x_bf,
                       float* __restrict__ Mpart) {
    const int bx = blockIdx.x;
    const int ks = bx & 7;                  // split-K slice, pinned per XCD
    const int nt = (bx >> 3) & 1;
    const int mt = bx >> 4;
    const int b0 = mt << 7, n0 = nt << 7;
    const int tid  = threadIdx.x;
    const int lane = tid & 63, wave = tid >> 6;
    const int l15 = lane & 15, l4 = lane >> 4;

    // s tile: [32 j][132 r] f32 (pad to 132 -> broadcast-clean)
    __shared__ __align__(16) float Sl[32 * 132];
    for (int idx = tid; idx < 4096; idx += 256) {
        int r = idx >> 5, j = idx & 31;
        int jg = ks * 32 + j;
        float v = (jg < 128) ? st0[(size_t)(b0 + r) * 128 + jg]
                             : st1[(size_t)(b0 + r) * 128 + (jg - 128)];
        Sl[j * 132 + r] = v;
    }
    __syncthreads();                        // the ONLY barrier

    // B-frag bases, fragment-ordered Wt:
    // n16(nf) = nt*8 + wave*2 + nf; frag addr = ((n16*1024 + kchunk)*2+kst)*1024 + lane*16
    const unsigned char* rbn[2];
    #pragma unroll
    for (int nf = 0; nf < 2; ++nf)
        rbn[nf] = Wt + ((size_t)(nt * 8 + wave * 2 + nf) << 21) + lane * 16;
    const float* sB = Sl + l4 * 4;

    f32x4 racc[8][2];
    #pragma unroll
    for (int mf = 0; mf < 8; ++mf)
        #pragma unroll
        for (int nf = 0; nf < 2; ++nf)
            racc[mf][nf] = (f32x4){0.f, 0.f, 0.f, 0.f};
    const f32x4 zacc = (f32x4){0.f, 0.f, 0.f, 0.f};

    // chunk c in [0,128): q = c>>5 (x-quadrant), j = c&31 (local j)
    // kchunk(c) = ((ks*32 + j)*4 + q); byte offset = kchunk*2048 (+ kst*1024)
    auto kof = [&](int c) { return (size_t)(((ks * 32 + (c & 31)) * 4 + (c >> 5)) * 2048); };

    // depth-4 circular B prefetch: buf[d] holds chunk (c with c&3 == d)
    bf8 buf[4][2][2];                       // [slot][nf][kst]
    #pragma unroll
    for (int d = 0; d < 3; ++d) {           // prime slots 0..2 with chunks 0..2
        const size_t kd = kof(d);
        #pragma unroll
        for (int nf = 0; nf < 2; ++nf)
            #pragma unroll
            for (int kst = 0; kst < 2; ++kst)
                buf[d][nf][kst] = *(const bf8*)(rbn[nf] + kd + kst * 1024);
    }

    bf8 a[8][2];                            // x A-frags, reloaded at q boundary

    for (int cb = 0; cb < 128; cb += 4) {
        #pragma unroll
        for (int u = 0; u < 4; ++u) {
            const int c = cb + u;
            const int pp = c & 3;
            const int q = c >> 5, j = c & 31;
            if (j == 0) {                   // new x-quadrant: reload A-frags
                const __hip_bfloat16* xb = x_bf + q * 64 + l4 * 8;
                #pragma unroll
                for (int mf = 0; mf < 8; ++mf)
                    #pragma unroll
                    for (int kst = 0; kst < 2; ++kst)
                        a[mf][kst] = *(const bf8*)(xb + (size_t)(b0 + mf * 16 + l15) * 256 + kst * 32);
            }
            // prefetch chunk c+3 into slot (c+3)&3 (wrap harmless)
            {
                const size_t k3 = kof((c + 3) & 127);
                const int p3 = (c + 3) & 3;
                #pragma unroll
                for (int nf = 0; nf < 2; ++nf)
                    #pragma unroll
                    for (int kst = 0; kst < 2; ++kst)
                        buf[p3][nf][kst] = *(const bf8*)(rbn[nf] + k3 + kst * 1024);
            }
            // s broadcast values for this j
            f32x4 sv[8];
            #pragma unroll
            for (int mf = 0; mf < 8; ++mf)
                sv[mf] = *(const f32x4*)(sB + j * 132 + mf * 16);
            // 32 MFMA + f32 scale-accumulate
            #pragma unroll
            for (int nf = 0; nf < 2; ++nf) {
                bf8 bf0 = buf[pp][nf][0];
                bf8 bf1 = buf[pp][nf][1];
                #pragma unroll
                for (int mf = 0; mf < 8; ++mf) {
                    f32x4 m0 = __builtin_amdgcn_mfma_f32_16x16x32_bf16(a[mf][0], bf0, zacc, 0, 0, 0);
                    m0 = __builtin_amdgcn_mfma_f32_16x16x32_bf16(a[mf][1], bf1, m0, 0, 0, 0);
                    racc[mf][nf] += sv[mf] * m0;
                }
            }
        }
    }

    // split-K partial stores (regular stores: producer->consumer coherence)
    float* mp = Mpart + ((size_t)ks << 20);
    #pragma unroll
    for (int mf = 0; mf < 8; ++mf)
        #pragma unroll
        for (int nf = 0; nf < 2; ++nf) {
            int b = b0 + mf * 16 + l4 * 4;
            int n = n0 + wave * 32 + nf * 16 + l15;
            #pragma unroll
            for (int r = 0; r < 4; ++r)
                mp[(size_t)(b + r) * 256 + n] = racc[mf][nf][r];
        }
}

// ---------------- epilogue: reduce split-K, s@W3, activations, blend --------
__global__ void epilogue(const float* __restrict__ st0, const float* __restrict__ st1,
                         const float* __restrict__ b1, const float* __restrict__ b2,
                         const float* __restrict__ W3, const float* __restrict__ Mpart,
                         float* __restrict__ out) {
    const int tid = threadIdx.x;
    const int h = tid & 127, rg = tid >> 7;          // rg in {0,1}
    const int bbase = blockIdx.x * 8;                // 8 rows per block
    __shared__ float srow[8][256];
    #pragma unroll
    for (int i = 0; i < 8; ++i) {
        int idx = i * 256 + tid;
        int r = idx >> 8, j = idx & 255;
        float v = (j < 128) ? st0[(size_t)(bbase + r) * 128 + j]
                            : st1[(size_t)(bbase + r) * 128 + (j - 128)];
        srow[r][j] = v;
    }
    __syncthreads();
    float acc0 = 0.f, acc1 = 0.f, acc2 = 0.f, acc3 = 0.f;
    for (int j = 0; j < 256; ++j) {
        float w = W3[j * 128 + h];
        acc0 += srow[rg][j] * w;
        acc1 += srow[rg + 2][j] * w;
        acc2 += srow[rg + 4][j] * w;
        acc3 += srow[rg + 6][j] * w;
    }
    float accs[4] = {acc0, acc1, acc2, acc3};
    float bb1 = b1[h], bb2 = b2[h];
    #pragma unroll
    for (int i = 0; i < 4; ++i) {
        int b = bbase + rg + i * 2;
        float m1 = 0.f, m2 = 0.f;
        #pragma unroll
        for (int k = 0; k < 8; ++k) {
            m1 += Mpart[((size_t)k << 20) + (size_t)b * 256 + h];
            m2 += Mpart[((size_t)k << 20) + (size_t)b * 256 + 128 + h];
        }
        float u = 1.0f / (1.0f + expf(-(m2 + bb2)));
        float t = tanhf(m1 + bb1);
        out[(size_t)b * 128 + h] = u * t + (1.0f - u) * accs[i];
    }
}

extern "C" void kernel_launch(void* const* d_in, const int* in_sizes, int n_in,
                              void* d_out, int out_size, void* d_ws, size_t ws_size,
                              hipStream_t stream) {
    const float* in0 = (const float*)d_in[0];
    const float* in1 = (const float*)d_in[1];
    const float* st0 = (const float*)d_in[2];
    const float* st1 = (const float*)d_in[3];
    const float* W1  = (const float*)d_in[4];
    const float* b1  = (const float*)d_in[5];
    const float* W2  = (const float*)d_in[6];
    const float* b2  = (const float*)d_in[7];
    const float* W3  = (const float*)d_in[8];
    float* out = (float*)d_out;
    char* ws = (char*)d_ws;

    unsigned char* Wt   = (unsigned char*)(ws + WT_OFF);
    unsigned*      x_bf = (unsigned*)(ws + XBF_OFF);
    float*         Mp   = (float*)(ws + MP_OFF);

    prep_wx<<<9216, 256, 0, stream>>>(W1, W2, in0, in1, (uint4*)Wt, x_bf);
    gemm_p<<<512, 256, 0, stream>>>(Wt, st0, st1, (const __hip_bfloat16*)x_bf, Mp);
    epilogue<<<512, 256, 0, stream>>>(st0, st1, b1, b2, W3, Mp, out);
}